// Round 3
// baseline (2020.620 us; speedup 1.0000x reference)
//
#include <hip/hip_runtime.h>
#include <hip/hip_fp16.h>
#include <cstdint>
#include <cstddef>

#define B_ 128
#define T_ 2048
#define C_ 16
#define CO_ 128
#define H_ 128
#define G_ 512
#define WCV 192                 // conv/x0 worker blocks
#define NBLK (64 + WCV)         // 256 = 32 L0 + 32 L1 + workers
#define L2E  1.4426950408889634f
#define L2E2 2.8853900817779268f

typedef _Float16 half8 __attribute__((ext_vector_type(8)));
typedef float f32x4 __attribute__((ext_vector_type(4)));

__device__ __forceinline__ unsigned packh2f(float a, float b) {
  union { _Float16 h[2]; unsigned u; } x;
  x.h[0] = (_Float16)a; x.h[1] = (_Float16)b;
  return x.u;
}

__device__ __forceinline__ float rcpf(float x) { return __builtin_amdgcn_rcpf(x); }

__device__ __forceinline__ float exp2f_(float x) {
#if __has_builtin(__builtin_amdgcn_exp2f)
  return __builtin_amdgcn_exp2f(x);
#else
  return __expf(x * 0.6931471805599453f);
#endif
}

// Raw barrier WITHOUT the vmcnt(0) drain of __syncthreads().
__device__ __forceinline__ void block_sync() {
  asm volatile("s_waitcnt lgkmcnt(0)" ::: "memory");
  __builtin_amdgcn_s_barrier();
  asm volatile("" ::: "memory");
}

__device__ __forceinline__ int ld_rlx(const int* p) {
  return __hip_atomic_load(p, __ATOMIC_RELAXED, __HIP_MEMORY_SCOPE_AGENT);
}
__device__ __forceinline__ void st_rlx(int* p, int v) {
  __hip_atomic_store(p, v, __ATOMIC_RELAXED, __HIP_MEMORY_SCOPE_AGENT);
}

// Gates arrive PRE-SCALED: i,f,o by log2e; g by 2*log2e. One cell per call.
__device__ __forceinline__ float lstm_cell1(float iv, float fv, float gv,
                                            float ov, float& c) {
  gv = fminf(fmaxf(gv, -43.3f), 43.3f);
  float ei = exp2f_(-iv), ef = exp2f_(-fv), eg = exp2f_(gv);
  float P = (1.f + ei) * (eg + 1.f);
  float Q = 1.f + ef;
  float num = c * P + (eg - 1.f) * Q;
  float cN = num * rcpf(Q * P);
  c = cN;
  float cc = fminf(fmaxf(cN, -15.f), 15.f);
  float eo = exp2f_(-ov), ec = exp2f_(L2E2 * cc);
  return (ec - 1.f) * rcpf((1.f + eo) * (ec + 1.f));
}

// ---------------------------------------------------------------------------
// pack_kernel: fragment-ordered weight buffers (pre-scaled by log2e / 2log2e).
// ---------------------------------------------------------------------------
__global__ __launch_bounds__(256) void pack_kernel(
    const float* __restrict__ w_ih0, const float* __restrict__ w_hh0,
    const float* __restrict__ w_ih1, const float* __restrict__ w_hh1,
    const float* __restrict__ b_ih1, const float* __restrict__ b_hh1,
    uint4* __restrict__ Wf0, uint4* __restrict__ Wih1f,
    uint4* __restrict__ Whh1f, uint4* __restrict__ WB0f,
    f32x4* __restrict__ b1fD) {
  int tid = blockIdx.x * 256 + threadIdx.x;
  if (tid < 24576) {
    int u = tid & 8191, L = u & 63, s = (u >> 6) & 3, tl = (u >> 8) & 3, w = u >> 10;
    int which = tid >> 13;
    const float* src = (which == 0) ? w_hh0 : (which == 1) ? w_ih1 : w_hh1;
    uint4* dst = (which == 0) ? Wf0 : (which == 1) ? Wih1f : Whh1f;
    int m = (w + 8 * tl) * 16 + (L & 15);
    float sc = (tl == 2) ? L2E2 : L2E;
    int k0 = s * 32 + (L >> 4) * 8;
    const float* p = src + m * 128 + k0;
    uint4 o;
    o.x = packh2f(p[0] * sc, p[1] * sc); o.y = packh2f(p[2] * sc, p[3] * sc);
    o.z = packh2f(p[4] * sc, p[5] * sc); o.w = packh2f(p[6] * sc, p[7] * sc);
    dst[u] = o;
  } else if (tid < 32768) {
    int u = tid - 24576, L = u & 63, s = (u >> 6) & 3, nt = u >> 8;
    int g = nt * 16 + (L & 15);
    float sc = ((nt >> 3) == 2) ? L2E2 : L2E;
    int k0 = s * 32 + (L >> 4) * 8;
    const float* p = w_ih0 + g * 128 + k0;
    uint4 o;
    o.x = packh2f(p[0] * sc, p[1] * sc); o.y = packh2f(p[2] * sc, p[3] * sc);
    o.z = packh2f(p[4] * sc, p[5] * sc); o.w = packh2f(p[6] * sc, p[7] * sc);
    WB0f[u] = o;
  } else if (tid < 34816) {
    int u2 = tid - 32768;
    int tl = u2 & 3, L = (u2 >> 2) & 63, w = u2 >> 8;
    int q = L >> 4;
    float sc = (tl == 2) ? L2E2 : L2E;
    f32x4 o;
#pragma unroll
    for (int reg = 0; reg < 4; ++reg) {
      int row = (w + 8 * tl) * 16 + q * 4 + reg;
      o[reg] = (b_ih1[row] + b_hh1[row]) * sc;
    }
    b1fD[u2] = o;
  }
}

// ---------------------------------------------------------------------------
// persist_kernel — 2-stage chain + producers:
//  bid 0..31 : L0  (Whh0 recurrence + cell0, 1 cell/thread; ALSO computes
//                   z1(t-1) = Wih1·h0(t-1) sharing the B0 LDS reads, stores to
//                   z1f ring; publishes z1p = t-3 per 4-step window, counted
//                   vmcnt so prefetches stay in flight)
//  bid 32..63: L1  (z1f + b1 + Whh1 recurrence + cell1 + pool)
//  bid 64..  : conv+x0 producers (x0 ring)
// XCD: group g at bid (inv of grp=(rb&7)*4+(rb>>3)); L1 at bid+32 (same %8 =
// same XCD = b16). Flags: xready[tile*32+grp](2048) l0c@2048 z1p@2560 l1p@3072
// (each +grp*16).
// ---------------------------------------------------------------------------
__global__ __launch_bounds__(512, 1) void persist_kernel(
    const float* __restrict__ x, const float* __restrict__ conv_w,
    const float* __restrict__ conv_b, const float* __restrict__ b_ih0,
    const float* __restrict__ b_hh0,
    const uint4* __restrict__ Wf0, const uint4* __restrict__ Wih1f,
    const uint4* __restrict__ Whh1f, const uint4* __restrict__ WB0f,
    const f32x4* __restrict__ b1fD,
    uint4* __restrict__ x0f, uint4* __restrict__ z1f,
    float* __restrict__ psave, int* __restrict__ flags,
    int rmask, int rmask2) {
  __shared__ __align__(16) union {
    struct { float xs[34 * 16]; _Float16 yh[32 * 136]; _Float16 x0S[32 * 512]; } wk;
    struct { _Float16 h[2][16 * 136]; float red[8192]; } rc;
  } sm;

  int* xready = flags;          // [tile*32 + grp], 2048 ints
  int* l0c = flags + 2048;      // + grp*16 (L0 progress, x0-ring WAR)
  int* z1p = flags + 2560;      // + grp*16 (z1 visible through value-1)
  int* l1p = flags + 3072;      // + grp*16 (L1 completed steps, z1-ring WAR)

  const int bid = blockIdx.x;
  const int tid = threadIdx.x;
  const int w = tid >> 6, L = tid & 63, q = L >> 4, n = L & 15;

  if (bid < 64) {
    // ---------------- L0 / L1 recurrence (1 cell/thread) ----------------
    const bool isL0 = bid < 32;
    const int rb = isL0 ? bid : bid - 32;
    const int grp = (rb & 7) * 4 + (rb >> 3);   // b16 = grp>>2 = rb&7 = XCD
    half8 WA[4][4];
    {
      const uint4* Wsrc = isL0 ? Wf0 : Whh1f;
#pragma unroll
      for (int tl = 0; tl < 4; ++tl)
#pragma unroll
        for (int s = 0; s < 4; ++s)
          WA[tl][s] = __builtin_bit_cast(half8, Wsrc[((w * 4 + tl) * 4 + s) * 64 + L]);
    }
    half8 WI[4][4];
    if (isL0) {
#pragma unroll
      for (int tl = 0; tl < 4; ++tl)
#pragma unroll
        for (int s = 0; s < 4; ++s)
          WI[tl][s] = __builtin_bit_cast(half8, Wih1f[((w * 4 + tl) * 4 + s) * 64 + L]);
    }
    f32x4 b1v[4];
    if (!isL0) {
#pragma unroll
      for (int tl = 0; tl < 4; ++tl) b1v[tl] = b1fD[(w * 64 + L) * 4 + tl];
    }

    float cst = 0.f, pool = 0.f;
    for (int idx = tid; idx < 2176; idx += 512) ((unsigned*)sm.rc.h)[idx] = 0u;
    __syncthreads();

    const int n4 = n & 3;
    const int n16 = (grp & 3) * 4 + n4;           // batch within 16-group
    const int uc = w * 16 + (L >> 2);             // this thread's cell unit
    const int bc = L & 3;                         // this thread's cell batch
    const int Lsrc = (L & 0x30) | (L & 3);
    const int rsrc = (L >> 2) & 3;
    float* red = sm.rc.red;

    const int b16 = grp >> 2;
    const uint4* rp = (isL0 ? x0f : z1f) +
        (((size_t)b16 * 8 + w) * 64 + (q * 16 + n16)) * 2;
    const int rmk = isL0 ? rmask : rmask2;
    // z1 store base (L0; only lanes n<4 store): lane slot q*16 + n16
    uint4* zdst = z1f + (((size_t)b16 * 8 + w) * 64 + (q * 16 + (grp & 3) * 4 + n)) * 2;
    const int R2 = rmask2 + 1;
    uint4 pa[4], pb[4];

    for (int g = 0; g < 64; ++g) {
      const int p0g = g * 32;
      if (tid == 0) {
        if (isL0) {
          while (ld_rlx(&xready[g * 32 + grp]) < 4) __builtin_amdgcn_s_sleep(2);
          if (g < 63)
            while (ld_rlx(&xready[(g + 1) * 32 + grp]) < 4) __builtin_amdgcn_s_sleep(2);
          if (p0g + 32 > R2) {  // z1-ring WAR vs L1
            const int need = p0g + 40 - R2;
            while (ld_rlx(&l1p[grp * 16]) < need) __builtin_amdgcn_s_sleep(8);
          }
        } else {
          int tgt = p0g + 40; if (tgt > T_) tgt = T_;
          while (ld_rlx(&z1p[grp * 16]) < tgt) __builtin_amdgcn_s_sleep(1);
        }
        __builtin_amdgcn_fence(__ATOMIC_ACQUIRE, "agent");
      }
      block_sync();
      if (g == 0) {
#pragma unroll
        for (int k = 0; k < 4; ++k) {
          pa[k] = rp[(size_t)k * 8192];
          pb[k] = rp[(size_t)k * 8192 + 1];
        }
      }
#pragma unroll 1
      for (int io = 0; io < 8; ++io) {
#pragma unroll
        for (int k = 0; k < 4; ++k) {
          const int t = p0g + io * 4 + k;
          const int c = t & 1, p = c ^ 1;
          // B0 = h(t-1) fragments (shared by recurrence and z1 MFMAs)
          half8 B0[4];
#pragma unroll
          for (int s = 0; s < 4; ++s)
            B0[s] = *(const half8*)&sm.rc.h[p][n4 * 136 + s * 32 + q * 8];
          f32x4 acc[4];
          {
            half8 xlo = __builtin_bit_cast(half8, pa[k]);
            half8 xhi = __builtin_bit_cast(half8, pb[k]);
            acc[0] = (f32x4){(float)xlo[0], (float)xlo[1], (float)xlo[2], (float)xlo[3]};
            acc[1] = (f32x4){(float)xlo[4], (float)xlo[5], (float)xlo[6], (float)xlo[7]};
            acc[2] = (f32x4){(float)xhi[0], (float)xhi[1], (float)xhi[2], (float)xhi[3]};
            acc[3] = (f32x4){(float)xhi[4], (float)xhi[5], (float)xhi[6], (float)xhi[7]};
            if (!isL0) {
              acc[0] += b1v[0]; acc[1] += b1v[1];
              acc[2] += b1v[2]; acc[3] += b1v[3];
            }
          }
#pragma unroll
          for (int s = 0; s < 4; ++s)
#pragma unroll
            for (int tl = 0; tl < 4; ++tl)
              acc[tl] = __builtin_amdgcn_mfma_f32_16x16x32_f16(WA[tl][s], B0[s], acc[tl], 0, 0, 0);

          f32x4 zacc[4];
          if (isL0) {
            // z1(t-1) = Wih1 · h0(t-1); off critical path (rides MFMA pipe)
#pragma unroll
            for (int tl = 0; tl < 4; ++tl) zacc[tl] = (f32x4){0.f, 0.f, 0.f, 0.f};
#pragma unroll
            for (int s = 0; s < 4; ++s)
#pragma unroll
              for (int tl = 0; tl < 4; ++tl)
                zacc[tl] = __builtin_amdgcn_mfma_f32_16x16x32_f16(WI[tl][s], B0[s], zacc[tl], 0, 0, 0);
          }

          {
            int tn = t + 4; if (tn > T_ - 1) tn = T_ - 1;
            const size_t so = (size_t)(tn & rmk) * 8192;
            pa[k] = rp[so];
            pb[k] = rp[so + 1];
          }

          // wave-local gate redistribution: 1 cell/thread afterwards
#pragma unroll
          for (int tl = 0; tl < 4; ++tl)
            *(f32x4*)&red[((w * 4 + tl) * 64 + L) * 4] = acc[tl];
          asm volatile("s_waitcnt lgkmcnt(0)" ::: "memory");
          float gi = red[((w * 4 + 0) * 64 + Lsrc) * 4 + rsrc];
          float gf = red[((w * 4 + 1) * 64 + Lsrc) * 4 + rsrc];
          float gg = red[((w * 4 + 2) * 64 + Lsrc) * 4 + rsrc];
          float go = red[((w * 4 + 3) * 64 + Lsrc) * 4 + rsrc];
          float hv = lstm_cell1(gi, gf, gg, go, cst);
          if (!isL0) pool += hv;
          sm.rc.h[c][bc * 136 + uc] = (_Float16)hv;

          if (isL0) {
            uint4 zo0, zo1;
            zo0.x = packh2f(zacc[0][0], zacc[0][1]); zo0.y = packh2f(zacc[0][2], zacc[0][3]);
            zo0.z = packh2f(zacc[1][0], zacc[1][1]); zo0.w = packh2f(zacc[1][2], zacc[1][3]);
            zo1.x = packh2f(zacc[2][0], zacc[2][1]); zo1.y = packh2f(zacc[2][2], zacc[2][3]);
            zo1.z = packh2f(zacc[3][0], zacc[3][1]); zo1.w = packh2f(zacc[3][2], zacc[3][3]);
            if (n < 4) {
              const size_t zs = (size_t)((t - 1) & rmask2) * 8192;
              zdst[zs] = zo0;
              zdst[zs + 1] = zo1;
            }
            if (k == 3)  // 4 VM ops/step; oldest window's ops retired at 12
              asm volatile("s_waitcnt vmcnt(12)" ::: "memory");
          }
          block_sync();
          if (k == 3 && tid == 0 && isL0)
            st_rlx(&z1p[grp * 16], t - 3);  // z1 steps < t-3 visible
        }
      }
      if (tid == 0) {
        if (isL0) st_rlx(&l0c[grp * 16], p0g + 32);
        else st_rlx(&l1p[grp * 16], p0g + 32);
      }
    }
    if (isL0) {
      // epilogue: z1(T-1) from h0(T-1) (parity (T_-1)&1 == 1)
      half8 B0[4];
#pragma unroll
      for (int s = 0; s < 4; ++s)
        B0[s] = *(const half8*)&sm.rc.h[1][n4 * 136 + s * 32 + q * 8];
      f32x4 zacc[4];
#pragma unroll
      for (int tl = 0; tl < 4; ++tl) zacc[tl] = (f32x4){0.f, 0.f, 0.f, 0.f};
#pragma unroll
      for (int s = 0; s < 4; ++s)
#pragma unroll
        for (int tl = 0; tl < 4; ++tl)
          zacc[tl] = __builtin_amdgcn_mfma_f32_16x16x32_f16(WI[tl][s], B0[s], zacc[tl], 0, 0, 0);
      uint4 zo0, zo1;
      zo0.x = packh2f(zacc[0][0], zacc[0][1]); zo0.y = packh2f(zacc[0][2], zacc[0][3]);
      zo0.z = packh2f(zacc[1][0], zacc[1][1]); zo0.w = packh2f(zacc[1][2], zacc[1][3]);
      zo1.x = packh2f(zacc[2][0], zacc[2][1]); zo1.y = packh2f(zacc[2][2], zacc[2][3]);
      zo1.z = packh2f(zacc[3][0], zacc[3][1]); zo1.w = packh2f(zacc[3][2], zacc[3][3]);
      if (n < 4) {
        const size_t zs = (size_t)((T_ - 1) & rmask2) * 8192;
        zdst[zs] = zo0;
        zdst[zs + 1] = zo1;
      }
      asm volatile("s_waitcnt vmcnt(0)" ::: "memory");
      __builtin_amdgcn_s_barrier();
      if (tid == 0)
        __hip_atomic_store(&z1p[grp * 16], T_, __ATOMIC_RELEASE,
                           __HIP_MEMORY_SCOPE_AGENT);
    } else {
      psave[(size_t)(grp * 4 + bc) * 128 + uc] = pool;
    }
  } else {
    // ---------------- conv + x0 projection workers ----------------
    const int wi = bid - 64;
    const int co = tid & 127;
    float cw[48];
#pragma unroll
    for (int i = 0; i < 12; ++i) {
      const float4 v = *(const float4*)(conv_w + co * 48 + i * 4);
      cw[i * 4 + 0] = v.x; cw[i * 4 + 1] = v.y;
      cw[i * 4 + 2] = v.z; cw[i * 4 + 3] = v.w;
    }
    const float cb = conv_b[co];
    half8 WB[4][4];
#pragma unroll
    for (int nt4 = 0; nt4 < 4; ++nt4)
#pragma unroll
      for (int s = 0; s < 4; ++s)
        WB[nt4][s] = __builtin_bit_cast(half8, WB0f[((w * 4 + nt4) * 4 + s) * 64 + L]);
    float b0v[4];
#pragma unroll
    for (int nt4 = 0; nt4 < 4; ++nt4) {
      int gg = (w * 4 + nt4) * 16 + n;
      b0v[nt4] = (b_ih0[gg] + b_hh0[gg]) * (((gg >> 7) == 2) ? L2E2 : L2E);
    }
    const int R = rmask + 1;

    for (int u = wi; u < 8192; u += WCV) {
      const int tile = u >> 7, b = u & 127;
      const int t0c = tile * 32;
      if (t0c + 40 > R) {
        const int need = t0c + 40 - R;
        if (tid == 0)
          while (ld_rlx(&l0c[(b >> 2) * 16]) < need)
            __builtin_amdgcn_s_sleep(8);
      }
      __syncthreads();

      for (int idx = tid; idx < 544; idx += 512) {
        int row = idx >> 4, cc2 = idx & 15;
        int gt = t0c - 1 + row;
        sm.wk.xs[idx] = (gt >= 0 && gt < T_) ? x[((size_t)b * T_ + gt) * C_ + cc2] : 0.f;
      }
      __syncthreads();

#pragma unroll
      for (int pp = 0; pp < 8; ++pp) {
        int r = pp * 4 + (tid >> 7);
        float acc = cb;
#pragma unroll
        for (int c16 = 0; c16 < 16; ++c16)
#pragma unroll
          for (int kk = 0; kk < 3; ++kk)
            acc += sm.wk.xs[(r + kk) * 16 + c16] * cw[c16 * 3 + kk];
        acc = acc >= 0.f ? acc : 0.01f * acc;
        sm.wk.yh[r * 136 + co] = (_Float16)acc;
      }
      __syncthreads();

#pragma unroll
      for (int mt = 0; mt < 2; ++mt) {
        half8 A[4];
#pragma unroll
        for (int s = 0; s < 4; ++s)
          A[s] = *(const half8*)&sm.wk.yh[(mt * 16 + n) * 136 + s * 32 + q * 8];
#pragma unroll
        for (int nt4 = 0; nt4 < 4; ++nt4) {
          f32x4 acc = {b0v[nt4], b0v[nt4], b0v[nt4], b0v[nt4]};
#pragma unroll
          for (int s = 0; s < 4; ++s)
            acc = __builtin_amdgcn_mfma_f32_16x16x32_f16(A[s], WB[nt4][s], acc, 0, 0, 0);
          int tau = w * 4 + nt4;
          int off = (tau & 7) * 64 + (n >> 2) * 16 + (tau >> 3) * 4 + (n & 3);
#pragma unroll
          for (int reg = 0; reg < 4; ++reg)
            sm.wk.x0S[(mt * 16 + q * 4 + reg) * 512 + off] = (_Float16)acc[reg];
        }
      }
      __syncthreads();

      const int bn = b & 15, bb16 = b >> 4;
      const int trb = t0c & rmask;
#pragma unroll
      for (int kk = 0; kk < 2; ++kk) {
        int cc = kk * 512 + tid;
        int r = cc >> 5, wq = cc & 31;
        int w2 = wq >> 2, q2 = wq & 3;
        const uint4* src = (const uint4*)&sm.wk.x0S[r * 512 + wq * 16];
        size_t gidx = ((((size_t)(trb + r) * 8 + bb16) * 8 + w2) * 64 + (bn + 16 * q2)) * 2;
        x0f[gidx] = src[0];
        x0f[gidx + 1] = src[1];
      }
      asm volatile("s_waitcnt vmcnt(0)" ::: "memory");
      __syncthreads();
      if (tid == 0)
        __hip_atomic_fetch_add(&xready[tile * 32 + (b >> 2)], 1, __ATOMIC_RELEASE,
                               __HIP_MEMORY_SCOPE_AGENT);
    }
  }
}

// ---------------------------------------------------------------------------
__global__ __launch_bounds__(128) void final_kernel(
    const float* __restrict__ psave, const float* __restrict__ lin_w,
    const float* __restrict__ lin_b, float* __restrict__ out) {
  int b = threadIdx.x;
  float acc = 0.f;
  const f32x4* pv = (const f32x4*)(psave + (size_t)b * 128);
  const f32x4* lw = (const f32x4*)lin_w;
#pragma unroll
  for (int u = 0; u < 32; ++u) {
    f32x4 v = pv[u], l = lw[u];
    acc += v[0] * l[0] + v[1] * l[1] + v[2] * l[2] + v[3] * l[3];
  }
  out[b] = acc * (1.0f / (float)T_) + lin_b[0];
}

// ---------------------------------------------------------------------------
extern "C" void kernel_launch(void* const* d_in, const int* in_sizes, int n_in,
                              void* d_out, int out_size, void* d_ws, size_t ws_size,
                              hipStream_t stream) {
  (void)in_sizes; (void)n_in; (void)out_size;
  const float* x      = (const float*)d_in[0];
  const float* conv_w = (const float*)d_in[1];
  const float* conv_b = (const float*)d_in[2];
  const float* w_ih0  = (const float*)d_in[3];
  const float* w_hh0  = (const float*)d_in[4];
  const float* b_ih0  = (const float*)d_in[5];
  const float* b_hh0  = (const float*)d_in[6];
  const float* w_ih1  = (const float*)d_in[7];
  const float* w_hh1  = (const float*)d_in[8];
  const float* b_ih1  = (const float*)d_in[9];
  const float* b_hh1  = (const float*)d_in[10];
  const float* lin_w  = (const float*)d_in[11];
  const float* lin_b  = (const float*)d_in[12];

  char* ws = (char*)d_ws;
  uint4* Wf0   = (uint4*)(ws + 0);        // 131072
  uint4* Wih1f = (uint4*)(ws + 131072);   // 131072
  uint4* Whh1f = (uint4*)(ws + 262144);   // 131072
  uint4* WB0f  = (uint4*)(ws + 393216);   // 131072
  f32x4* b1fD  = (f32x4*)(ws + 524288);   // 32768
  float* psave = (float*)(ws + 557056);   // 65536 ([128 b][128 u] f32)
  int*   flags = (int*)(ws + 622592);     // 16384 (3584 ints used)
  const size_t base = 622592 + 16384;     // 638976

  int R = 256, R2 = 256;  // x0 ring, z1 ring (steps)
  while (R > 64 && base + ((size_t)R + (size_t)R2) * 131072 > ws_size) {
    R >>= 1; R2 >>= 1;
  }
  uint4* x0f = (uint4*)(ws + base);
  uint4* z1f = (uint4*)(ws + base + (size_t)R * 131072);

  hipMemsetAsync(flags, 0, 16384, stream);
  pack_kernel<<<136, 256, 0, stream>>>(w_ih0, w_hh0, w_ih1, w_hh1, b_ih1, b_hh1,
                                       Wf0, Wih1f, Whh1f, WB0f, b1fD);
  persist_kernel<<<NBLK, 512, 0, stream>>>(
      x, conv_w, conv_b, b_ih0, b_hh0, Wf0, Wih1f, Whh1f, WB0f, b1fD,
      x0f, z1f, psave, flags, R - 1, R2 - 1);
  final_kernel<<<1, 128, 0, stream>>>(psave, lin_w, lin_b, (float*)d_out);
}

// Round 5
// 1625.495 us; speedup vs baseline: 1.2431x; 1.2431x over previous
//
#include <hip/hip_runtime.h>
#include <hip/hip_fp16.h>
#include <cstdint>
#include <cstddef>

#define B_ 128
#define T_ 2048
#define C_ 16
#define CO_ 128
#define H_ 128
#define G_ 512
#define WCV 184                 // conv/x0 worker blocks
#define NBLK (72 + WCV)         // 256 = 32 L0 + 8 Z1 + 32 L1 + workers
#define L2E  1.4426950408889634f
#define L2E2 2.8853900817779268f

typedef _Float16 half8 __attribute__((ext_vector_type(8)));
typedef float f32x4 __attribute__((ext_vector_type(4)));

__device__ __forceinline__ unsigned packh2f(float a, float b) {
  union { _Float16 h[2]; unsigned u; } x;
  x.h[0] = (_Float16)a; x.h[1] = (_Float16)b;
  return x.u;
}

__device__ __forceinline__ float rcpf(float x) { return __builtin_amdgcn_rcpf(x); }

__device__ __forceinline__ float exp2f_(float x) {
#if __has_builtin(__builtin_amdgcn_exp2f)
  return __builtin_amdgcn_exp2f(x);
#else
  return __expf(x * 0.6931471805599453f);
#endif
}

// Raw barrier WITHOUT the vmcnt(0) drain of __syncthreads().
__device__ __forceinline__ void block_sync() {
  asm volatile("s_waitcnt lgkmcnt(0)" ::: "memory");
  __builtin_amdgcn_s_barrier();
  asm volatile("" ::: "memory");
}

__device__ __forceinline__ int ld_rlx(const int* p) {
  return __hip_atomic_load(p, __ATOMIC_RELAXED, __HIP_MEMORY_SCOPE_AGENT);
}
__device__ __forceinline__ void st_rlx(int* p, int v) {
  __hip_atomic_store(p, v, __ATOMIC_RELAXED, __HIP_MEMORY_SCOPE_AGENT);
}

// Gates arrive PRE-SCALED: i,f,o by log2e; g by 2*log2e. One cell per call.
__device__ __forceinline__ float lstm_cell1(float iv, float fv, float gv,
                                            float ov, float& c) {
  gv = fminf(fmaxf(gv, -43.3f), 43.3f);
  float ei = exp2f_(-iv), ef = exp2f_(-fv), eg = exp2f_(gv);
  float P = (1.f + ei) * (eg + 1.f);
  float Q = 1.f + ef;
  float num = c * P + (eg - 1.f) * Q;
  float cN = num * rcpf(Q * P);
  c = cN;
  float cc = fminf(fmaxf(cN, -15.f), 15.f);
  float eo = exp2f_(-ov), ec = exp2f_(L2E2 * cc);
  return (ec - 1.f) * rcpf((1.f + eo) * (ec + 1.f));
}

// ---------------------------------------------------------------------------
// pack_kernel: fragment-ordered weight buffers (pre-scaled by log2e / 2log2e).
// ---------------------------------------------------------------------------
__global__ __launch_bounds__(256) void pack_kernel(
    const float* __restrict__ w_ih0, const float* __restrict__ w_hh0,
    const float* __restrict__ w_ih1, const float* __restrict__ w_hh1,
    const float* __restrict__ b_ih1, const float* __restrict__ b_hh1,
    uint4* __restrict__ Wf0, uint4* __restrict__ Wih1f,
    uint4* __restrict__ Whh1f, uint4* __restrict__ WB0f,
    f32x4* __restrict__ b1fD) {
  int tid = blockIdx.x * 256 + threadIdx.x;
  if (tid < 24576) {
    int u = tid & 8191, L = u & 63, s = (u >> 6) & 3, tl = (u >> 8) & 3, w = u >> 10;
    int which = tid >> 13;
    const float* src = (which == 0) ? w_hh0 : (which == 1) ? w_ih1 : w_hh1;
    uint4* dst = (which == 0) ? Wf0 : (which == 1) ? Wih1f : Whh1f;
    int m = (w + 8 * tl) * 16 + (L & 15);
    float sc = (tl == 2) ? L2E2 : L2E;
    int k0 = s * 32 + (L >> 4) * 8;
    const float* p = src + m * 128 + k0;
    uint4 o;
    o.x = packh2f(p[0] * sc, p[1] * sc); o.y = packh2f(p[2] * sc, p[3] * sc);
    o.z = packh2f(p[4] * sc, p[5] * sc); o.w = packh2f(p[6] * sc, p[7] * sc);
    dst[u] = o;
  } else if (tid < 32768) {
    int u = tid - 24576, L = u & 63, s = (u >> 6) & 3, nt = u >> 8;
    int g = nt * 16 + (L & 15);
    float sc = ((nt >> 3) == 2) ? L2E2 : L2E;
    int k0 = s * 32 + (L >> 4) * 8;
    const float* p = w_ih0 + g * 128 + k0;
    uint4 o;
    o.x = packh2f(p[0] * sc, p[1] * sc); o.y = packh2f(p[2] * sc, p[3] * sc);
    o.z = packh2f(p[4] * sc, p[5] * sc); o.w = packh2f(p[6] * sc, p[7] * sc);
    WB0f[u] = o;
  } else if (tid < 34816) {
    int u2 = tid - 32768;
    int tl = u2 & 3, L = (u2 >> 2) & 63, w = u2 >> 8;
    int q = L >> 4;
    float sc = (tl == 2) ? L2E2 : L2E;
    f32x4 o;
#pragma unroll
    for (int reg = 0; reg < 4; ++reg) {
      int row = (w + 8 * tl) * 16 + q * 4 + reg;
      o[reg] = (b_ih1[row] + b_hh1[row]) * sc;
    }
    b1fD[u2] = o;
  }
}

// ---------------------------------------------------------------------------
// persist_kernel — 3-stage chain + producers (R2 structure):
//  bid 0..31 : L0  (Whh0 + cell0; NO LDS redistribution: per-thread register
//                   cndmask select of gate reg r=(L>>2)&3 -> 1 cell/thread;
//                   h4 buffer stride 144 halfs = conflict-free B0 reads)
//  bid 32..39: Z1  (z1 = b1 + Wih1.h0 from h0g -> z1f ring; bias added HERE
//                   and ONLY here)
//  bid 40..71: L1  (same select scheme + pool; z1f already contains b1)
//  bid 72..  : conv+x0 producers (x0 ring)
// ---------------------------------------------------------------------------
__global__ __launch_bounds__(512, 1) void persist_kernel(
    const float* __restrict__ x, const float* __restrict__ conv_w,
    const float* __restrict__ conv_b, const float* __restrict__ b_ih0,
    const float* __restrict__ b_hh0,
    const uint4* __restrict__ Wf0, const uint4* __restrict__ Wih1f,
    const uint4* __restrict__ Whh1f, const uint4* __restrict__ WB0f,
    const f32x4* __restrict__ b1fD,
    uint4* __restrict__ x0f, uint2* __restrict__ h0g, uint4* __restrict__ z1f,
    float* __restrict__ psave, int* __restrict__ flags,
    int rmask, int rmask2) {
  __shared__ __align__(16) union {
    struct { float xs[34 * 16]; _Float16 yh[32 * 136]; _Float16 x0S[32 * 512]; } wk;
    struct { _Float16 h[2][16 * 136]; } rc;     // Z1: 16 batches, stride 136
    struct { _Float16 h4[2][576]; } rc4;        // L0/L1: 4 batches, stride 144
  } sm;

  int* xready = flags;          // [tile*32 + grp], 2048 ints
  int* l0p = flags + 2048;      // + grp*16
  int* l0c = flags + 2560;      // + grp*16
  int* z1p = flags + 3072;      // + b16*16
  int* l1p = flags + 3200;      // + grp*16

  const int bid = blockIdx.x;
  const int tid = threadIdx.x;
  const int w = tid >> 6, L = tid & 63, q = L >> 4, n = L & 15;

  if (bid < 32 || (bid >= 40 && bid < 72)) {
    // ---------------- L0 / L1: recurrence, 1 cell/thread, no redist ---------
    const bool isL0 = bid < 32;
    const int rb = isL0 ? bid : bid - 40;
    const int grp = (rb & 7) * 4 + (rb >> 3);   // 4-batch group id, XCD = rb&7
    half8 WA[4][4];
    {
      const uint4* Wsrc = isL0 ? Wf0 : Whh1f;
#pragma unroll
      for (int tl = 0; tl < 4; ++tl)
#pragma unroll
        for (int s = 0; s < 4; ++s)
          WA[tl][s] = __builtin_bit_cast(half8, Wsrc[((w * 4 + tl) * 4 + s) * 64 + L]);
    }
    float cst = 0.f, pool = 0.f;
    for (int idx = tid; idx < 576; idx += 512) ((unsigned*)sm.rc4.h4)[idx] = 0u;
    __syncthreads();

    const int n4 = n & 3;
    const int n16 = (grp & 3) * 4 + n4;           // batch within 16-group
    const int uc = w * 16 + (L >> 2);             // this thread's cell unit
    const int bc = L & 3;                         // this thread's cell batch
    const int rsel = (L >> 2) & 3;                // which acc reg is mine
    const bool sb0 = (rsel & 1) != 0, sb1 = (rsel & 2) != 0;

    const uint4* rp = (isL0 ? x0f : z1f) +
        (((size_t)(grp >> 2) * 8 + w) * 64 + (q * 16 + n16)) * 2;
    const int rmk = isL0 ? rmask : rmask2;
    uint2* hgp = h0g + (((grp >> 2) * 16 + ((grp & 3) * 4 + (tid & 3))) * 32 + (tid >> 2));
    uint4 pa[4], pb[4];

    for (int g = 0; g < 64; ++g) {
      const int p0g = g * 32;
      if (tid == 0) {
        if (isL0) {
          while (ld_rlx(&xready[g * 32 + grp]) < 4) __builtin_amdgcn_s_sleep(2);
          if (g < 63)
            while (ld_rlx(&xready[(g + 1) * 32 + grp]) < 4) __builtin_amdgcn_s_sleep(2);
        } else {
          int tgt = p0g + 40; if (tgt > T_) tgt = T_;
          while (ld_rlx(&z1p[(grp >> 2) * 16]) < tgt) __builtin_amdgcn_s_sleep(1);
        }
        __builtin_amdgcn_fence(__ATOMIC_ACQUIRE, "agent");
      }
      block_sync();
      if (g == 0) {
#pragma unroll
        for (int k = 0; k < 4; ++k) {
          pa[k] = rp[(size_t)k * 8192];
          pb[k] = rp[(size_t)k * 8192 + 1];
        }
      }
#pragma unroll 1
      for (int io = 0; io < 8; ++io) {
#pragma unroll
        for (int k = 0; k < 4; ++k) {
          const int t = p0g + io * 4 + k;
          const int c = t & 1, p = c ^ 1;
          f32x4 acc[4];
          {
            half8 xlo = __builtin_bit_cast(half8, pa[k]);
            half8 xhi = __builtin_bit_cast(half8, pb[k]);
            acc[0] = (f32x4){(float)xlo[0], (float)xlo[1], (float)xlo[2], (float)xlo[3]};
            acc[1] = (f32x4){(float)xlo[4], (float)xlo[5], (float)xlo[6], (float)xlo[7]};
            acc[2] = (f32x4){(float)xhi[0], (float)xhi[1], (float)xhi[2], (float)xhi[3]};
            acc[3] = (f32x4){(float)xhi[4], (float)xhi[5], (float)xhi[6], (float)xhi[7]};
          }
          half8 B0[4];
#pragma unroll
          for (int s = 0; s < 4; ++s)
            B0[s] = *(const half8*)&sm.rc4.h4[p][n4 * 144 + s * 32 + q * 8];
#pragma unroll
          for (int s = 0; s < 4; ++s)
#pragma unroll
            for (int tl = 0; tl < 4; ++tl)
              acc[tl] = __builtin_amdgcn_mfma_f32_16x16x32_f16(WA[tl][s], B0[s], acc[tl], 0, 0, 0);

          {
            int tn = t + 4; if (tn > T_ - 1) tn = T_ - 1;
            const size_t so = (size_t)(tn & rmk) * 8192;
            pa[k] = rp[so];
            pb[k] = rp[so + 1];
          }

          // register select (cndmask): this thread's cell = reg rsel
          float gi, gf, gg, go;
          {
            float lo, hi;
            lo = sb0 ? acc[0][1] : acc[0][0]; hi = sb0 ? acc[0][3] : acc[0][2];
            gi = sb1 ? hi : lo;
            lo = sb0 ? acc[1][1] : acc[1][0]; hi = sb0 ? acc[1][3] : acc[1][2];
            gf = sb1 ? hi : lo;
            lo = sb0 ? acc[2][1] : acc[2][0]; hi = sb0 ? acc[2][3] : acc[2][2];
            gg = sb1 ? hi : lo;
            lo = sb0 ? acc[3][1] : acc[3][0]; hi = sb0 ? acc[3][3] : acc[3][2];
            go = sb1 ? hi : lo;
          }
          float hv = lstm_cell1(gi, gf, gg, go, cst);
          if (!isL0) pool += hv;
          sm.rc4.h4[c][bc * 144 + uc] = (_Float16)hv;

          block_sync();
          if (isL0) {
            if (k == 3) {
              // t-3's h0g store retired after vmcnt(8) (3 VM ops/step, waves 0-1)
              asm volatile("s_waitcnt vmcnt(8)" ::: "memory");
              if (tid == 0) st_rlx(&l0p[grp * 16], t - 3);
            }
            if (tid < 128)
              hgp[(size_t)t * 4096] =
                  *(const uint2*)&sm.rc4.h4[c][(tid & 3) * 144 + (tid >> 2) * 4];
          }
        }
      }
      if (tid == 0) {
        if (isL0) st_rlx(&l0c[grp * 16], p0g + 32);
        else if (g & 1) st_rlx(&l1p[grp * 16], p0g + 32);
      }
    }
    if (isL0) {
      asm volatile("s_waitcnt vmcnt(0)" ::: "memory");
      __builtin_amdgcn_s_barrier();
      if (tid == 0)
        __hip_atomic_store(&l0p[grp * 16], T_, __ATOMIC_RELEASE,
                           __HIP_MEMORY_SCOPE_AGENT);
    } else {
      psave[(size_t)(grp * 4 + bc) * 128 + uc] = pool;
    }
  } else if (bid < 40) {
    // ---------------- Z1: z1(t) = b1 + Wih1 . h0(t) (16 batches) ------------
    const int b16 = bid - 32;
    half8 WI[4][4];
#pragma unroll
    for (int tl = 0; tl < 4; ++tl)
#pragma unroll
      for (int s = 0; s < 4; ++s)
        WI[tl][s] = __builtin_bit_cast(half8, Wih1f[((w * 4 + tl) * 4 + s) * 64 + L]);
    f32x4 b1v[4];
#pragma unroll
    for (int tl = 0; tl < 4; ++tl) b1v[tl] = b1fD[(w * 64 + L) * 4 + tl];

    const int n2 = tid >> 5, jq = tid & 31;
    const uint2* hsrc = h0g + ((b16 * 16 + n2) * 32 + jq);
    uint4* zdst = z1f + (((size_t)b16 * 8 + w) * 64 + L) * 2;
    const int R2 = rmask2 + 1;
    uint2 hpf[4];

#pragma unroll 1
    for (int p0 = 0; p0 < T_; p0 += 4) {
      if (tid < 4) {
        const int gj = b16 * 4 + tid;
        while (ld_rlx(&l0p[gj * 16]) < p0 + 4) __builtin_amdgcn_s_sleep(1);
        __builtin_amdgcn_fence(__ATOMIC_ACQUIRE, "agent");
      } else if (tid >= 4 && tid < 8 && p0 + 4 > R2) {
        const int gj = b16 * 4 + (tid - 4);
        const int need = p0 + 12 - R2;  // z1-ring WAR margin
        while (ld_rlx(&l1p[gj * 16]) < need) __builtin_amdgcn_s_sleep(8);
      }
      block_sync();
#pragma unroll
      for (int k = 0; k < 4; ++k) hpf[k] = hsrc[(size_t)(p0 + k) * 4096];
#pragma unroll
      for (int k = 0; k < 4; ++k) {
        const int t = p0 + k;
        const int c = t & 1;
        *(uint2*)&sm.rc.h[c][n2 * 136 + jq * 4] = hpf[k];
        block_sync();
        half8 B[4];
#pragma unroll
        for (int s = 0; s < 4; ++s)
          B[s] = *(const half8*)&sm.rc.h[c][n * 136 + s * 32 + q * 8];
        f32x4 acc[4];
#pragma unroll
        for (int tl = 0; tl < 4; ++tl) acc[tl] = b1v[tl];
#pragma unroll
        for (int s = 0; s < 4; ++s)
#pragma unroll
          for (int tl = 0; tl < 4; ++tl)
            acc[tl] = __builtin_amdgcn_mfma_f32_16x16x32_f16(WI[tl][s], B[s], acc[tl], 0, 0, 0);
        uint4 o0, o1;
        o0.x = packh2f(acc[0][0], acc[0][1]); o0.y = packh2f(acc[0][2], acc[0][3]);
        o0.z = packh2f(acc[1][0], acc[1][1]); o0.w = packh2f(acc[1][2], acc[1][3]);
        o1.x = packh2f(acc[2][0], acc[2][1]); o1.y = packh2f(acc[2][2], acc[2][3]);
        o1.z = packh2f(acc[3][0], acc[3][1]); o1.w = packh2f(acc[3][2], acc[3][3]);
        const size_t zs = (size_t)(t & rmask2) * 8192;
        zdst[zs] = o0;
        zdst[zs + 1] = o1;
      }
      // publish value p0: window p0-4's stores retired after vmcnt(12)
      asm volatile("s_waitcnt vmcnt(12)" ::: "memory");
      block_sync();
      if (tid == 0) st_rlx(&z1p[b16 * 16], p0);
    }
    asm volatile("s_waitcnt vmcnt(0)" ::: "memory");
    __builtin_amdgcn_s_barrier();
    if (tid == 0)
      __hip_atomic_store(&z1p[b16 * 16], T_, __ATOMIC_RELEASE,
                         __HIP_MEMORY_SCOPE_AGENT);
  } else {
    // ---------------- conv + x0 projection workers ----------------
    const int wi = bid - 72;
    const int co = tid & 127;
    float cw[48];
#pragma unroll
    for (int i = 0; i < 12; ++i) {
      const float4 v = *(const float4*)(conv_w + co * 48 + i * 4);
      cw[i * 4 + 0] = v.x; cw[i * 4 + 1] = v.y;
      cw[i * 4 + 2] = v.z; cw[i * 4 + 3] = v.w;
    }
    const float cb = conv_b[co];
    half8 WB[4][4];
#pragma unroll
    for (int nt4 = 0; nt4 < 4; ++nt4)
#pragma unroll
      for (int s = 0; s < 4; ++s)
        WB[nt4][s] = __builtin_bit_cast(half8, WB0f[((w * 4 + nt4) * 4 + s) * 64 + L]);
    float b0v[4];
#pragma unroll
    for (int nt4 = 0; nt4 < 4; ++nt4) {
      int gg = (w * 4 + nt4) * 16 + n;
      b0v[nt4] = (b_ih0[gg] + b_hh0[gg]) * (((gg >> 7) == 2) ? L2E2 : L2E);
    }
    const int R = rmask + 1;

    for (int u = wi; u < 8192; u += WCV) {
      const int tile = u >> 7, b = u & 127;
      const int t0c = tile * 32;
      if (t0c + 40 > R) {
        const int need = t0c + 40 - R;
        if (tid == 0)
          while (ld_rlx(&l0c[(b >> 2) * 16]) < need)
            __builtin_amdgcn_s_sleep(8);
      }
      __syncthreads();

      for (int idx = tid; idx < 544; idx += 512) {
        int row = idx >> 4, cc2 = idx & 15;
        int gt = t0c - 1 + row;
        sm.wk.xs[idx] = (gt >= 0 && gt < T_) ? x[((size_t)b * T_ + gt) * C_ + cc2] : 0.f;
      }
      __syncthreads();

#pragma unroll
      for (int pp = 0; pp < 8; ++pp) {
        int r = pp * 4 + (tid >> 7);
        float acc = cb;
#pragma unroll
        for (int c16 = 0; c16 < 16; ++c16)
#pragma unroll
          for (int kk = 0; kk < 3; ++kk)
            acc += sm.wk.xs[(r + kk) * 16 + c16] * cw[c16 * 3 + kk];
        acc = acc >= 0.f ? acc : 0.01f * acc;
        sm.wk.yh[r * 136 + co] = (_Float16)acc;
      }
      __syncthreads();

#pragma unroll
      for (int mt = 0; mt < 2; ++mt) {
        half8 A[4];
#pragma unroll
        for (int s = 0; s < 4; ++s)
          A[s] = *(const half8*)&sm.wk.yh[(mt * 16 + n) * 136 + s * 32 + q * 8];
#pragma unroll
        for (int nt4 = 0; nt4 < 4; ++nt4) {
          f32x4 acc = {b0v[nt4], b0v[nt4], b0v[nt4], b0v[nt4]};
#pragma unroll
          for (int s = 0; s < 4; ++s)
            acc = __builtin_amdgcn_mfma_f32_16x16x32_f16(A[s], WB[nt4][s], acc, 0, 0, 0);
          int tau = w * 4 + nt4;
          int off = (tau & 7) * 64 + (n >> 2) * 16 + (tau >> 3) * 4 + (n & 3);
#pragma unroll
          for (int reg = 0; reg < 4; ++reg)
            sm.wk.x0S[(mt * 16 + q * 4 + reg) * 512 + off] = (_Float16)acc[reg];
        }
      }
      __syncthreads();

      const int bn = b & 15, bb16 = b >> 4;
      const int trb = t0c & rmask;
#pragma unroll
      for (int kk = 0; kk < 2; ++kk) {
        int cc = kk * 512 + tid;
        int r = cc >> 5, wq = cc & 31;
        int w2 = wq >> 2, q2 = wq & 3;
        const uint4* src = (const uint4*)&sm.wk.x0S[r * 512 + wq * 16];
        size_t gidx = ((((size_t)(trb + r) * 8 + bb16) * 8 + w2) * 64 + (bn + 16 * q2)) * 2;
        x0f[gidx] = src[0];
        x0f[gidx + 1] = src[1];
      }
      asm volatile("s_waitcnt vmcnt(0)" ::: "memory");
      __syncthreads();
      if (tid == 0)
        __hip_atomic_fetch_add(&xready[tile * 32 + (b >> 2)], 1, __ATOMIC_RELEASE,
                               __HIP_MEMORY_SCOPE_AGENT);
    }
  }
}

// ---------------------------------------------------------------------------
__global__ __launch_bounds__(128) void final_kernel(
    const float* __restrict__ psave, const float* __restrict__ lin_w,
    const float* __restrict__ lin_b, float* __restrict__ out) {
  int b = threadIdx.x;
  float acc = 0.f;
  const f32x4* pv = (const f32x4*)(psave + (size_t)b * 128);
  const f32x4* lw = (const f32x4*)lin_w;
#pragma unroll
  for (int u = 0; u < 32; ++u) {
    f32x4 v = pv[u], l = lw[u];
    acc += v[0] * l[0] + v[1] * l[1] + v[2] * l[2] + v[3] * l[3];
  }
  out[b] = acc * (1.0f / (float)T_) + lin_b[0];
}

// ---------------------------------------------------------------------------
extern "C" void kernel_launch(void* const* d_in, const int* in_sizes, int n_in,
                              void* d_out, int out_size, void* d_ws, size_t ws_size,
                              hipStream_t stream) {
  (void)in_sizes; (void)n_in; (void)out_size;
  const float* x      = (const float*)d_in[0];
  const float* conv_w = (const float*)d_in[1];
  const float* conv_b = (const float*)d_in[2];
  const float* w_ih0  = (const float*)d_in[3];
  const float* w_hh0  = (const float*)d_in[4];
  const float* b_ih0  = (const float*)d_in[5];
  const float* b_hh0  = (const float*)d_in[6];
  const float* w_ih1  = (const float*)d_in[7];
  const float* w_hh1  = (const float*)d_in[8];
  const float* b_ih1  = (const float*)d_in[9];
  const float* b_hh1  = (const float*)d_in[10];
  const float* lin_w  = (const float*)d_in[11];
  const float* lin_b  = (const float*)d_in[12];

  char* ws = (char*)d_ws;
  uint4* Wf0   = (uint4*)(ws + 0);        // 131072
  uint4* Wih1f = (uint4*)(ws + 131072);   // 131072
  uint4* Whh1f = (uint4*)(ws + 262144);   // 131072
  uint4* WB0f  = (uint4*)(ws + 393216);   // 131072
  f32x4* b1fD  = (f32x4*)(ws + 524288);   // 32768
  float* psave = (float*)(ws + 557056);   // 65536 ([128 b][128 u] f32)
  int*   flags = (int*)(ws + 622592);     // 16384 (3712 ints used)
  uint2* h0g   = (uint2*)(ws + 638976);   // 67108864 (full-T h0 stream)
  const size_t base = 638976 + 67108864;  // 67747840

  int R = 256, R2 = 256;  // x0 ring, z1 ring (steps)
  while (R > 64 && base + ((size_t)R + (size_t)R2) * 131072 > ws_size) {
    R >>= 1; R2 >>= 1;
  }
  uint4* x0f = (uint4*)(ws + base);
  uint4* z1f = (uint4*)(ws + base + (size_t)R * 131072);

  hipMemsetAsync(flags, 0, 16384, stream);
  pack_kernel<<<136, 256, 0, stream>>>(w_ih0, w_hh0, w_ih1, w_hh1, b_ih1, b_hh1,
                                       Wf0, Wih1f, Whh1f, WB0f, b1fD);
  persist_kernel<<<NBLK, 512, 0, stream>>>(
      x, conv_w, conv_b, b_ih0, b_hh0, Wf0, Wih1f, Whh1f, WB0f, b1fD,
      x0f, h0g, z1f, psave, flags, R - 1, R2 - 1);
  final_kernel<<<1, 128, 0, stream>>>(psave, lin_w, lin_b, (float*)d_out);
}